// Round 3
// baseline (460.534 us; speedup 1.0000x reference)
//
#include <hip/hip_runtime.h>

// Maxwell RNN scan: gamma_n = (1-h) gamma_{n-1} + h eps_n, h = 0.5*dt
// sig_n = 2.5*eps_n - gamma_{n-1}   (pre-update gamma)
// One WAVE per row: wave-shuffle affine-composition scan, no LDS, no barriers,
// double-buffered register prefetch so loads overlap the dependent scan chain.

typedef float fx4 __attribute__((ext_vector_type(4)));  // native vec for NT store

constexpr int   T_LEN  = 8192;
constexpr int   V      = 16;             // elements per lane per tile
constexpr int   LTILE  = 64 * V;         // 1024 elements per wave-tile
constexpr int   NT     = T_LEN / LTILE;  // 8 tiles per row
constexpr int   WPB    = 4;              // waves per block
constexpr int   THREADS = WPB * 64;
constexpr float KCOEF  = 0.5f;           // E_MOD / ETA

__global__ __launch_bounds__(THREADS) void maxwell_wave_kernel(
    const float* __restrict__ eps, const float* __restrict__ dtv,
    float* __restrict__ out)
{
    const int lane   = threadIdx.x & 63;
    const int wid    = threadIdx.x >> 6;
    const int rowIdx = blockIdx.x * WPB + wid;
    const size_t row = (size_t)rowIdx * T_LEN;
    const float* e_row = eps + row;
    const float* d_row = dtv + row;
    float*       o_row = out + row;

    fx4 ebuf[2][4], dbuf[2][4];

    // Prefetch tile 0.
    {
        const float* ep = e_row + lane * V;
        const float* dp = d_row + lane * V;
        #pragma unroll
        for (int i = 0; i < 4; ++i) {
            ebuf[0][i] = *(const fx4*)(ep + 4 * i);
            dbuf[0][i] = *(const fx4*)(dp + 4 * i);
        }
    }

    float gamma = 0.0f;  // row carry (uniform across the wave)

    for (int t = 0; t < NT; ++t) {
        const int cur = t & 1, nxt = cur ^ 1;

        // Issue next tile's loads before touching current tile's registers.
        if (t + 1 < NT) {
            const float* ep = e_row + (t + 1) * LTILE + lane * V;
            const float* dp = d_row + (t + 1) * LTILE + lane * V;
            #pragma unroll
            for (int i = 0; i < 4; ++i) {
                ebuf[nxt][i] = *(const fx4*)(ep + 4 * i);
                dbuf[nxt][i] = *(const fx4*)(dp + 4 * i);
            }
        }

        float ev[V], hv[V];
        #pragma unroll
        for (int i = 0; i < 4; ++i) {
            #pragma unroll
            for (int j = 0; j < 4; ++j) {
                ev[4*i+j] = ebuf[cur][i][j];
                hv[4*i+j] = dbuf[cur][i][j] * KCOEF;
            }
        }

        // Compose this lane's chunk: gamma_out = A*gamma_in + Bc
        float A = 1.0f, Bc = 0.0f;
        #pragma unroll
        for (int j = 0; j < V; ++j) {
            const float a = 1.0f - hv[j];
            Bc = fmaf(a, Bc, hv[j] * ev[j]);
            A *= a;
        }

        // Inclusive 64-lane scan under affine composition (later ∘ earlier).
        float sa = A, sb = Bc;
        #pragma unroll
        for (int off = 1; off < 64; off <<= 1) {
            const float pa = __shfl_up(sa, off, 64);
            const float pb = __shfl_up(sb, off, 64);
            if (lane >= off) { sb = fmaf(sa, pb, sb); sa *= pa; }
        }

        // Exclusive transform for this lane, applied to the tile-entering gamma.
        float ea = __shfl_up(sa, 1, 64);
        float eb = __shfl_up(sb, 1, 64);
        if (lane == 0) { ea = 1.0f; eb = 0.0f; }
        float g = fmaf(ea, gamma, eb);   // gamma entering this lane's chunk

        // Replay chunk: emit sigma, advance gamma.
        float sg[V];
        #pragma unroll
        for (int j = 0; j < V; ++j) {
            sg[j] = fmaf(2.5f, ev[j], -g);       // E_INF*e + E*(e - g)
            g = fmaf(hv[j], ev[j] - g, g);       // g += dt*k*(e - g)
        }

        float* op = o_row + t * LTILE + lane * V;
        #pragma unroll
        for (int i = 0; i < 4; ++i) {
            fx4 s4 = {sg[4*i+0], sg[4*i+1], sg[4*i+2], sg[4*i+3]};
            __builtin_nontemporal_store(s4, (fx4*)(op + 4 * i));
        }

        // Advance the row carry by the wave-total transform (lane 63 inclusive).
        const float ta = __shfl(sa, 63, 64);
        const float tb = __shfl(sb, 63, 64);
        gamma = fmaf(ta, gamma, tb);
    }
}

extern "C" void kernel_launch(void* const* d_in, const int* in_sizes, int n_in,
                              void* d_out, int out_size, void* d_ws, size_t ws_size,
                              hipStream_t stream) {
    const float* eps = (const float*)d_in[0];
    const float* dtv = (const float*)d_in[1];
    float* out = (float*)d_out;
    const int B = in_sizes[0] / T_LEN;       // 4096 rows
    maxwell_wave_kernel<<<B / WPB, THREADS, 0, stream>>>(eps, dtv, out);
}